// Round 3
// baseline (599.558 us; speedup 1.0000x reference)
//
#include <hip/hip_runtime.h>
#include <math.h>

#define IN_DIM 512
#define NH 4
#define OD 64
#define HD 256   // NH*OD

typedef float  floatx4 __attribute__((ext_vector_type(4)));
typedef short  shortx8 __attribute__((ext_vector_type(8)));

__device__ __forceinline__ unsigned short f2bf(float x) {
    unsigned int u = __float_as_uint(x);
    u += 0x7fffu + ((u >> 16) & 1u);          // round-to-nearest-even
    return (unsigned short)(u >> 16);
}
__device__ __forceinline__ float bf2f(unsigned short u) {
    return __uint_as_float(((unsigned int)u) << 16);
}

// ---------------------------------------------------------------- prep
// zero deg arrays; W fp32 [512][256] -> Wt bf16 [256][512];
// x fp32 -> xb bf16 row-major (streaming, cvt hides under BW) when xb!=null.
__global__ void prep_kernel(const float* __restrict__ W, ushort* __restrict__ Wt,
                            const float* __restrict__ x, ushort* __restrict__ xb,
                            int* __restrict__ deg_src, int* __restrict__ deg_dst,
                            int M) {
    int t = blockIdx.x * blockDim.x + threadIdx.x;
    if (t < M) { deg_src[t] = 0; deg_dst[t] = 0; }
    if (t < 256 * 64) {
        int n = t >> 6;
        int k8 = (t & 63) * 8;
        shortx8 v;
        #pragma unroll
        for (int j = 0; j < 8; ++j) v[j] = (short)f2bf(W[(size_t)(k8 + j) * HD + n]);
        *(shortx8*)&Wt[(size_t)n * IN_DIM + k8] = v;
    }
    if (xb && t < M * 64) {
        int row = t >> 6;
        int k8 = (t & 63) * 8;
        const float* gp = &x[(size_t)row * IN_DIM + k8];
        float4 v0 = *(const float4*)gp;
        float4 v1 = *(const float4*)(gp + 4);
        shortx8 v;
        v[0] = (short)f2bf(v0.x); v[1] = (short)f2bf(v0.y);
        v[2] = (short)f2bf(v0.z); v[3] = (short)f2bf(v0.w);
        v[4] = (short)f2bf(v1.x); v[5] = (short)f2bf(v1.y);
        v[6] = (short)f2bf(v1.z); v[7] = (short)f2bf(v1.w);
        *(shortx8*)&xb[(size_t)row * IN_DIM + k8] = v;
    }
}

// ---------------------------------------------------------------- MFMA GEMM (+scores)
// h_bf16 = bf16(x) @ W : tile 64(M) x 256(N), BK=64, 4 waves (each 64m x 64n).
// XB=true: A staged via global_load_lds from pre-converted xb (no VALU cvt on
// the barrier-synced path). Garbage rows past M only pollute discarded output
// rows (MFMA rows are independent). XB=false: legacy register staging.
template<bool XB>
__global__ __launch_bounds__(256) void gemm_kernel(const float* __restrict__ x,
                                                   const ushort* __restrict__ xb,
                                                   const ushort* __restrict__ Wt,
                                                   ushort* __restrict__ h,
                                                   const float* __restrict__ a,
                                                   float2* __restrict__ ssi,
                                                   float* __restrict__ s_dst,
                                                   int M) {
    __shared__ ushort As[64 * 64];     // [row m][64 k]  8 KB
    __shared__ ushort Bs[256 * 64];    // [row n][64 k] 32 KB
    const int tid = threadIdx.x;
    const int lane = tid & 63;
    const int w = tid >> 6;
    const int bm = blockIdx.x * 64;
    const int wn = w * 64;
    const int lm = lane & 15;          // fragment row
    const int lq = lane >> 4;          // quad
    floatx4 acc[4][4];
    #pragma unroll
    for (int i = 0; i < 4; ++i)
        #pragma unroll
        for (int j = 0; j < 4; ++j) acc[i][j] = (floatx4){0.f, 0.f, 0.f, 0.f};

    for (int k0 = 0; k0 < IN_DIM; k0 += 64) {
        if constexpr (XB) {
            #pragma unroll
            for (int j = 0; j < 2; ++j) {
                int ch = j * 256 + tid;
                int row = ch >> 3;
                int c = (ch & 7) ^ (row & 7);
                const ushort* gp = &xb[(size_t)(bm + row) * IN_DIM + k0 + c * 8];
                __builtin_amdgcn_global_load_lds(
                    (const __attribute__((address_space(1))) void*)gp,
                    (__attribute__((address_space(3))) void*)&As[(size_t)(j * 256 + wn) * 8],
                    16, 0, 0);
            }
        } else {
            #pragma unroll
            for (int j = 0; j < 2; ++j) {
                int ch = tid * 2 + j;
                int row = ch >> 3;
                int c = (ch & 7) ^ (row & 7);
                int gr = bm + row;
                shortx8 v = (shortx8){0, 0, 0, 0, 0, 0, 0, 0};
                if (gr < M) {
                    const float* gp = &x[(size_t)gr * IN_DIM + k0 + c * 8];
                    float4 v0 = *(const float4*)gp;
                    float4 v1 = *(const float4*)(gp + 4);
                    v[0] = (short)f2bf(v0.x); v[1] = (short)f2bf(v0.y);
                    v[2] = (short)f2bf(v0.z); v[3] = (short)f2bf(v0.w);
                    v[4] = (short)f2bf(v1.x); v[5] = (short)f2bf(v1.y);
                    v[6] = (short)f2bf(v1.z); v[7] = (short)f2bf(v1.w);
                }
                *(shortx8*)&As[ch * 8] = v;
            }
        }
        #pragma unroll
        for (int j = 0; j < 8; ++j) {
            int ch = j * 256 + tid;
            int row = ch >> 3;
            int c = (ch & 7) ^ (row & 7);
            const ushort* gp = &Wt[(size_t)row * IN_DIM + k0 + c * 8];
            __builtin_amdgcn_global_load_lds(
                (const __attribute__((address_space(1))) void*)gp,
                (__attribute__((address_space(3))) void*)&Bs[(size_t)(j * 256 + wn) * 8],
                16, 0, 0);
        }
        __syncthreads();
        #pragma unroll
        for (int kk = 0; kk < 2; ++kk) {
            shortx8 af[4], bfr[4];
            #pragma unroll
            for (int mt = 0; mt < 4; ++mt) {
                int row = mt * 16 + lm;
                int c = (kk * 4 + lq) ^ (row & 7);
                af[mt] = *(const shortx8*)&As[row * 64 + c * 8];
            }
            #pragma unroll
            for (int nt = 0; nt < 4; ++nt) {
                int row = wn + nt * 16 + lm;
                int c = (kk * 4 + lq) ^ (row & 7);
                bfr[nt] = *(const shortx8*)&Bs[row * 64 + c * 8];
            }
            #pragma unroll
            for (int mt = 0; mt < 4; ++mt)
                #pragma unroll
                for (int nt = 0; nt < 4; ++nt)
                    acc[mt][nt] = __builtin_amdgcn_mfma_f32_16x16x32_bf16(
                        af[mt], bfr[nt], acc[mt][nt], 0, 0, 0);
        }
        __syncthreads();
    }
    // ---- fused scores: s_src[m,w], s_dst[m,w] from fp32 acc
    float as_l[4], ad_l[4];
    #pragma unroll
    for (int nt = 0; nt < 4; ++nt) {
        as_l[nt] = a[w * 2 * OD + nt * 16 + lm];
        ad_l[nt] = a[w * 2 * OD + OD + nt * 16 + lm];
    }
    #pragma unroll
    for (int mt = 0; mt < 4; ++mt)
        #pragma unroll
        for (int r = 0; r < 4; ++r) {
            float ps = 0.f, pd = 0.f;
            #pragma unroll
            for (int nt = 0; nt < 4; ++nt) {
                float v = acc[mt][nt][r];
                ps += v * as_l[nt];
                pd += v * ad_l[nt];
            }
            #pragma unroll
            for (int off = 1; off < 16; off <<= 1) {
                ps += __shfl_xor(ps, off, 64);
                pd += __shfl_xor(pd, off, 64);
            }
            int m = bm + mt * 16 + lq * 4 + r;
            if (m < M && lm == 0) {
                ssi[m * NH + w].x = ps;
                s_dst[m * NH + w] = pd;
            }
        }
    // ---- h store: C/D layout col=lane&15, row=(lane>>4)*4+reg  [m89/m91]
    #pragma unroll
    for (int mt = 0; mt < 4; ++mt)
        #pragma unroll
        for (int r = 0; r < 4; ++r) {
            int m = bm + mt * 16 + lq * 4 + r;
            if (m < M) {
                #pragma unroll
                for (int nt = 0; nt < 4; ++nt)
                    h[(size_t)m * HD + wn + nt * 16 + lm] = f2bf(acc[mt][nt][r]);
            }
        }
}

// ---------------------------------------------------------------- count (int atomics only)
__global__ void count_kernel(const int2* __restrict__ edges,
                             int* __restrict__ deg_src, int* __restrict__ deg_dst,
                             int E) {
    int i = blockIdx.x * blockDim.x + threadIdx.x;
    if (i >= E) return;
    int2 e = edges[i];
    atomicAdd(&deg_src[e.x], 1);
    atomicAdd(&deg_dst[e.y], 1);
}

// ---------------------------------------------------------------- scan
// block 0 scans deg_src -> ptr_src/cur_src; block 1 scans deg_dst -> ptr_dst/cur_dst.
__global__ __launch_bounds__(1024) void scan2_kernel(const int* __restrict__ deg_src,
                                                     const int* __restrict__ deg_dst,
                                                     int* __restrict__ ptr_src,
                                                     int* __restrict__ ptr_dst,
                                                     int* __restrict__ cur_src,
                                                     int* __restrict__ cur_dst, int M) {
    const int* deg = blockIdx.x ? deg_dst : deg_src;
    int* ptr = blockIdx.x ? ptr_dst : ptr_src;
    int* cur = blockIdx.x ? cur_dst : cur_src;
    __shared__ int sdata[1024];
    const int t = threadIdx.x;
    const int C = (M + 1023) >> 10;
    const int base = t * C;
    int sum = 0;
    for (int j = 0; j < C; ++j) {
        int i = base + j;
        if (i < M) sum += deg[i];
    }
    sdata[t] = sum;
    __syncthreads();
    for (int off = 1; off < 1024; off <<= 1) {
        int v = (t >= off) ? sdata[t - off] : 0;
        __syncthreads();
        sdata[t] += v;
        __syncthreads();
    }
    int run = sdata[t] - sum;          // exclusive base for this thread's segment
    for (int j = 0; j < C; ++j) {
        int i = base + j;
        if (i < M) {
            ptr[i] = run;
            cur[i] = run;
            run += deg[i];
        }
    }
    if (t == 1023) ptr[M] = run;
}

// ---------------------------------------------------------------- scatter
// csr_sd[src buckets] = dst id; csr_ds[dst buckets] = src id. int atomics only.
__global__ void scatter_kernel(const int2* __restrict__ edges,
                               int* __restrict__ cur_src, int* __restrict__ cur_dst,
                               int* __restrict__ csr_sd, int* __restrict__ csr_ds,
                               int E) {
    int i = blockIdx.x * blockDim.x + threadIdx.x;
    if (i >= E) return;
    int2 e = edges[i];
    int ps = atomicAdd(&cur_src[e.x], 1);
    csr_sd[ps] = e.y;
    int pd = atomicAdd(&cur_dst[e.y], 1);
    csr_ds[pd] = e.x;
}

// ---------------------------------------------------------------- src sums (CSR)
// one wave per src node; lane = slot*4+head: 16 slots stride over the node's
// contiguous edge list (no chase, no imbalance). 4 lanes of a slot read the
// same dst id (broadcast; 16 consecutive ints per wave-inst) then coalesced
// s_dst float4-group. shfl reduce over slots; lanes 0..3 write inv_sum.
__global__ __launch_bounds__(256) void src_sum_kernel(const int* __restrict__ ptr_src,
                                                      const int* __restrict__ csr_sd,
                                                      float2* __restrict__ ssi,
                                                      const float* __restrict__ s_dst, int M) {
    int lane = threadIdx.x & 63;
    int n = blockIdx.x * 4 + (threadIdx.x >> 6);
    if (n >= M) return;
    int slot = lane >> 2;
    int hd = lane & 3;
    float ss = ssi[n * NH + hd].x;
    float sum = 0.f;
    int beg = ptr_src[n], end = ptr_src[n + 1];
    for (int e = beg + slot; e < end; e += 16) {
        int d = csr_sd[e];
        float sd = s_dst[(size_t)d * NH + hd];
        float a0 = ss + sd;
        a0 = a0 > 0.f ? a0 : 0.2f * a0;
        sum += __expf(a0);
    }
    sum += __shfl_xor(sum, 4, 64);
    sum += __shfl_xor(sum, 8, 64);
    sum += __shfl_xor(sum, 16, 64);
    sum += __shfl_xor(sum, 32, 64);
    if (lane < 4) ssi[n * NH + lane].y = 1.f / (sum + 1e-10f);
}

// ---------------------------------------------------------------- gather (CSR)
// one wave per dst node; halves take alternating edges of the contiguous list,
// 2x unrolled. No pointer chase: iteration i+1's loads are address-independent
// of iteration i, so the whole list pipelines. Lane covers 8 channels
// (shortx8 = 16B h-load). Halves combined by cross-half shfl; coalesced store.
__global__ __launch_bounds__(256) void gather_kernel(
        const int* __restrict__ ptr_dst, const int* __restrict__ csr_ds,
        const float2* __restrict__ ssi, const float* __restrict__ s_dst,
        const ushort* __restrict__ h, const float* __restrict__ bias,
        float* __restrict__ out, int M) {
    int lane = threadIdx.x & 63;
    int n = blockIdx.x * 4 + (threadIdx.x >> 6);
    if (n >= M) return;
    int half = lane >> 5;
    int l5 = lane & 31;
    int head = l5 >> 3;            // 8 lanes per head
    int c0 = l5 * 8;               // channel base 0..248
    float sdst = s_dst[n * NH + head];
    floatx4 accA = {0.f, 0.f, 0.f, 0.f}, accB = {0.f, 0.f, 0.f, 0.f};
    int beg = ptr_dst[n], end = ptr_dst[n + 1];
    int e = beg + half;

#define GAT_EDGE(SI, HU) do {                                                  \
        float es_ = (SI).x + sdst;                                             \
        es_ = es_ > 0.f ? es_ : 0.2f * es_;                                    \
        float al_ = __expf(es_) * (SI).y;                                      \
        accA.x += al_ * bf2f((ushort)(HU)[0]);                                 \
        accA.y += al_ * bf2f((ushort)(HU)[1]);                                 \
        accA.z += al_ * bf2f((ushort)(HU)[2]);                                 \
        accA.w += al_ * bf2f((ushort)(HU)[3]);                                 \
        accB.x += al_ * bf2f((ushort)(HU)[4]);                                 \
        accB.y += al_ * bf2f((ushort)(HU)[5]);                                 \
        accB.z += al_ * bf2f((ushort)(HU)[6]);                                 \
        accB.w += al_ * bf2f((ushort)(HU)[7]);                                 \
    } while (0)

    for (; e + 2 < end; e += 4) {
        int s0 = csr_ds[e];
        int s1 = csr_ds[e + 2];
        float2 si0 = ssi[(size_t)s0 * NH + head];
        float2 si1 = ssi[(size_t)s1 * NH + head];
        shortx8 h0 = *(const shortx8*)&h[(size_t)s0 * HD + c0];
        shortx8 h1 = *(const shortx8*)&h[(size_t)s1 * HD + c0];
        GAT_EDGE(si0, h0);
        GAT_EDGE(si1, h1);
    }
    if (e < end) {
        int s0 = csr_ds[e];
        float2 si0 = ssi[(size_t)s0 * NH + head];
        shortx8 h0 = *(const shortx8*)&h[(size_t)s0 * HD + c0];
        GAT_EDGE(si0, h0);
    }
#undef GAT_EDGE

    // combine the two halves (same channels, different edges)
    accA.x += __shfl_xor(accA.x, 32, 64); accA.y += __shfl_xor(accA.y, 32, 64);
    accA.z += __shfl_xor(accA.z, 32, 64); accA.w += __shfl_xor(accA.w, 32, 64);
    accB.x += __shfl_xor(accB.x, 32, 64); accB.y += __shfl_xor(accB.y, 32, 64);
    accB.z += __shfl_xor(accB.z, 32, 64); accB.w += __shfl_xor(accB.w, 32, 64);
    if (half == 0) {
        float4 b0 = *(const float4*)&bias[c0];
        float4 b1 = *(const float4*)&bias[c0 + 4];
        float4 o0 = make_float4(accA.x + b0.x, accA.y + b0.y, accA.z + b0.z, accA.w + b0.w);
        float4 o1 = make_float4(accB.x + b1.x, accB.y + b1.y, accB.z + b1.z, accB.w + b1.w);
        *(float4*)&out[(size_t)n * HD + c0] = o0;
        *(float4*)&out[(size_t)n * HD + c0 + 4] = o1;
    }
}

// ---------------------------------------------------------------- launch
extern "C" void kernel_launch(void* const* d_in, const int* in_sizes, int n_in,
                              void* d_out, int out_size, void* d_ws, size_t ws_size,
                              hipStream_t stream) {
    const float* x     = (const float*)d_in[0];
    const int2*  edges = (const int2*)d_in[1];
    const float* W     = (const float*)d_in[2];
    const float* a     = (const float*)d_in[3];
    const float* bias  = (const float*)d_in[4];
    float* out = (float*)d_out;
    const int M = in_sizes[0] / IN_DIM;   // 50000
    const int E = in_sizes[1] / 2;        // 800000

    char* p = (char*)d_ws;
    auto alloc = [&](size_t bytes) { char* q = p; p += (bytes + 255) & ~(size_t)255; return q; };
    ushort* hB      = (ushort*)alloc((size_t)M * HD * sizeof(ushort));       // 25.6 MB
    ushort* Wt      = (ushort*)alloc((size_t)HD * IN_DIM * sizeof(ushort));  // 256 KB
    float*  s_dst   = (float*)alloc((size_t)M * NH * sizeof(float));         // 800 KB
    float2* ssi     = (float2*)alloc((size_t)M * NH * sizeof(float2));       // {s_src, inv_sum}
    int*    deg_src = (int*)alloc((size_t)M * sizeof(int));
    int*    deg_dst = (int*)alloc((size_t)M * sizeof(int));
    int*    ptr_src = (int*)alloc(((size_t)M + 1) * sizeof(int));
    int*    ptr_dst = (int*)alloc(((size_t)M + 1) * sizeof(int));
    int*    cur_src = (int*)alloc((size_t)M * sizeof(int));
    int*    cur_dst = (int*)alloc((size_t)M * sizeof(int));
    int*    csr_sd  = (int*)alloc((size_t)E * sizeof(int));                  // 3.2 MB
    int*    csr_ds  = (int*)alloc((size_t)E * sizeof(int));                  // 3.2 MB
    // optional bf16 copy of x (pad 64 rows so gemm's DMA tile-tail stays in-bounds)
    size_t xb_bytes = (size_t)(M + 64) * IN_DIM * sizeof(ushort);            // 51.3 MB
    ushort* xb = nullptr;
    if ((size_t)(p - (char*)d_ws) + xb_bytes <= ws_size)
        xb = (ushort*)alloc(xb_bytes);

    int prep_threads = xb ? M * 64 : (M > 256 * 64 ? M : 256 * 64);
    prep_kernel<<<(prep_threads + 255) / 256, 256, 0, stream>>>(W, Wt, x, xb,
                                                                deg_src, deg_dst, M);
    if (xb)
        gemm_kernel<true><<<(M + 63) / 64, 256, 0, stream>>>(x, xb, Wt, hB, a,
                                                             ssi, s_dst, M);
    else
        gemm_kernel<false><<<(M + 63) / 64, 256, 0, stream>>>(x, xb, Wt, hB, a,
                                                              ssi, s_dst, M);
    count_kernel<<<(E + 255) / 256, 256, 0, stream>>>(edges, deg_src, deg_dst, E);
    scan2_kernel<<<2, 1024, 0, stream>>>(deg_src, deg_dst, ptr_src, ptr_dst,
                                         cur_src, cur_dst, M);
    scatter_kernel<<<(E + 255) / 256, 256, 0, stream>>>(edges, cur_src, cur_dst,
                                                        csr_sd, csr_ds, E);
    src_sum_kernel<<<(M + 3) / 4, 256, 0, stream>>>(ptr_src, csr_sd, ssi, s_dst, M);
    gather_kernel<<<(M + 3) / 4, 256, 0, stream>>>(ptr_dst, csr_ds, ssi, s_dst,
                                                   hB, bias, out, M);
}

// Round 4
// 371.012 us; speedup vs baseline: 1.6160x; 1.6160x over previous
//
#include <hip/hip_runtime.h>
#include <math.h>

#define IN_DIM 512
#define NH 4
#define OD 64
#define HD 256   // NH*OD

typedef float  floatx4 __attribute__((ext_vector_type(4)));
typedef short  shortx8 __attribute__((ext_vector_type(8)));

__device__ __forceinline__ unsigned short f2bf(float x) {
    unsigned int u = __float_as_uint(x);
    u += 0x7fffu + ((u >> 16) & 1u);          // round-to-nearest-even
    return (unsigned short)(u >> 16);
}
__device__ __forceinline__ float bf2f(unsigned short u) {
    return __uint_as_float(((unsigned int)u) << 16);
}

// ---------------------------------------------------------------- init
// head_src (16 chains/node) / head_dst (8 chains/node) = -1. 4.8 MB -> ~1 us.
__global__ void init_kernel(int* __restrict__ head_src, int* __restrict__ head_dst,
                            int M) {
    int t = blockIdx.x * blockDim.x + threadIdx.x;
    if (t < 16 * M) head_src[t] = -1;
    if (t < 8 * M) head_dst[t] = -1;
}

// ---------------------------------------------------------------- prep + link (fused)
// Streaming conversions (W->Wt bf16 [256][512]; x->xb bf16 row-major) hide
// under the link's random-atomic latency shadow (different resources:
// BW-bound vs fabric-RMW-bound).
// link: lock-free list push, 16 chains/src + 8 chains/dst; payload packed
// into next: next_src={next,dst}, next_dst={next,src}. Payload writes are
// COALESCED (indexed by edge id) - this is why lists beat CSR scatter here.
__global__ void prep_link_kernel(const float* __restrict__ W, ushort* __restrict__ Wt,
                                 const float* __restrict__ x, ushort* __restrict__ xb,
                                 const int2* __restrict__ edges,
                                 int* __restrict__ head_src, int2* __restrict__ next_src,
                                 int* __restrict__ head_dst, int2* __restrict__ next_dst,
                                 int M, int E) {
    int t = blockIdx.x * blockDim.x + threadIdx.x;
    if (t < E) {
        int2 e = edges[t];
        int ps = atomicExch(&head_src[16 * e.x + (t & 15)], t);
        next_src[t] = make_int2(ps, e.y);
        int pd = atomicExch(&head_dst[8 * e.y + (t & 7)], t);
        next_dst[t] = make_int2(pd, e.x);
    }
    if (t < 256 * 64) {
        int n = t >> 6;
        int k8 = (t & 63) * 8;
        shortx8 v;
        #pragma unroll
        for (int j = 0; j < 8; ++j) v[j] = (short)f2bf(W[(size_t)(k8 + j) * HD + n]);
        *(shortx8*)&Wt[(size_t)n * IN_DIM + k8] = v;
    }
    if (xb && t < M * 64) {
        int row = t >> 6;
        int k8 = (t & 63) * 8;
        const float* gp = &x[(size_t)row * IN_DIM + k8];
        float4 v0 = *(const float4*)gp;
        float4 v1 = *(const float4*)(gp + 4);
        shortx8 v;
        v[0] = (short)f2bf(v0.x); v[1] = (short)f2bf(v0.y);
        v[2] = (short)f2bf(v0.z); v[3] = (short)f2bf(v0.w);
        v[4] = (short)f2bf(v1.x); v[5] = (short)f2bf(v1.y);
        v[6] = (short)f2bf(v1.z); v[7] = (short)f2bf(v1.w);
        *(shortx8*)&xb[(size_t)row * IN_DIM + k8] = v;
    }
}

// ---------------------------------------------------------------- MFMA GEMM (+scores)
// h_bf16 = bf16(x) @ W : tile 64(M) x 256(N), BK=64, 4 waves (each 64m x 64n).
// XB=true: A staged via global_load_lds from pre-converted xb (no VALU cvt on
// the barrier-synced path). Garbage rows past M only pollute discarded output
// rows (MFMA rows are independent; xb has 64 pad rows so DMA stays in-bounds).
template<bool XB>
__global__ __launch_bounds__(256) void gemm_kernel(const float* __restrict__ x,
                                                   const ushort* __restrict__ xb,
                                                   const ushort* __restrict__ Wt,
                                                   ushort* __restrict__ h,
                                                   const float* __restrict__ a,
                                                   float2* __restrict__ ssi,
                                                   float* __restrict__ s_dst,
                                                   int M) {
    __shared__ ushort As[64 * 64];     // [row m][64 k]  8 KB
    __shared__ ushort Bs[256 * 64];    // [row n][64 k] 32 KB
    const int tid = threadIdx.x;
    const int lane = tid & 63;
    const int w = tid >> 6;
    const int bm = blockIdx.x * 64;
    const int wn = w * 64;
    const int lm = lane & 15;          // fragment row
    const int lq = lane >> 4;          // quad
    floatx4 acc[4][4];
    #pragma unroll
    for (int i = 0; i < 4; ++i)
        #pragma unroll
        for (int j = 0; j < 4; ++j) acc[i][j] = (floatx4){0.f, 0.f, 0.f, 0.f};

    for (int k0 = 0; k0 < IN_DIM; k0 += 64) {
        if constexpr (XB) {
            #pragma unroll
            for (int j = 0; j < 2; ++j) {
                int ch = j * 256 + tid;
                int row = ch >> 3;
                int c = (ch & 7) ^ (row & 7);
                const ushort* gp = &xb[(size_t)(bm + row) * IN_DIM + k0 + c * 8];
                __builtin_amdgcn_global_load_lds(
                    (const __attribute__((address_space(1))) void*)gp,
                    (__attribute__((address_space(3))) void*)&As[(size_t)(j * 256 + wn) * 8],
                    16, 0, 0);
            }
        } else {
            #pragma unroll
            for (int j = 0; j < 2; ++j) {
                int ch = tid * 2 + j;
                int row = ch >> 3;
                int c = (ch & 7) ^ (row & 7);
                int gr = bm + row;
                shortx8 v = (shortx8){0, 0, 0, 0, 0, 0, 0, 0};
                if (gr < M) {
                    const float* gp = &x[(size_t)gr * IN_DIM + k0 + c * 8];
                    float4 v0 = *(const float4*)gp;
                    float4 v1 = *(const float4*)(gp + 4);
                    v[0] = (short)f2bf(v0.x); v[1] = (short)f2bf(v0.y);
                    v[2] = (short)f2bf(v0.z); v[3] = (short)f2bf(v0.w);
                    v[4] = (short)f2bf(v1.x); v[5] = (short)f2bf(v1.y);
                    v[6] = (short)f2bf(v1.z); v[7] = (short)f2bf(v1.w);
                }
                *(shortx8*)&As[ch * 8] = v;
            }
        }
        #pragma unroll
        for (int j = 0; j < 8; ++j) {
            int ch = j * 256 + tid;
            int row = ch >> 3;
            int c = (ch & 7) ^ (row & 7);
            const ushort* gp = &Wt[(size_t)row * IN_DIM + k0 + c * 8];
            __builtin_amdgcn_global_load_lds(
                (const __attribute__((address_space(1))) void*)gp,
                (__attribute__((address_space(3))) void*)&Bs[(size_t)(j * 256 + wn) * 8],
                16, 0, 0);
        }
        __syncthreads();
        #pragma unroll
        for (int kk = 0; kk < 2; ++kk) {
            shortx8 af[4], bfr[4];
            #pragma unroll
            for (int mt = 0; mt < 4; ++mt) {
                int row = mt * 16 + lm;
                int c = (kk * 4 + lq) ^ (row & 7);
                af[mt] = *(const shortx8*)&As[row * 64 + c * 8];
            }
            #pragma unroll
            for (int nt = 0; nt < 4; ++nt) {
                int row = wn + nt * 16 + lm;
                int c = (kk * 4 + lq) ^ (row & 7);
                bfr[nt] = *(const shortx8*)&Bs[row * 64 + c * 8];
            }
            #pragma unroll
            for (int mt = 0; mt < 4; ++mt)
                #pragma unroll
                for (int nt = 0; nt < 4; ++nt)
                    acc[mt][nt] = __builtin_amdgcn_mfma_f32_16x16x32_bf16(
                        af[mt], bfr[nt], acc[mt][nt], 0, 0, 0);
        }
        __syncthreads();
    }
    // ---- fused scores: s_src[m,w], s_dst[m,w] from fp32 acc
    float as_l[4], ad_l[4];
    #pragma unroll
    for (int nt = 0; nt < 4; ++nt) {
        as_l[nt] = a[w * 2 * OD + nt * 16 + lm];
        ad_l[nt] = a[w * 2 * OD + OD + nt * 16 + lm];
    }
    #pragma unroll
    for (int mt = 0; mt < 4; ++mt)
        #pragma unroll
        for (int r = 0; r < 4; ++r) {
            float ps = 0.f, pd = 0.f;
            #pragma unroll
            for (int nt = 0; nt < 4; ++nt) {
                float v = acc[mt][nt][r];
                ps += v * as_l[nt];
                pd += v * ad_l[nt];
            }
            #pragma unroll
            for (int off = 1; off < 16; off <<= 1) {
                ps += __shfl_xor(ps, off, 64);
                pd += __shfl_xor(pd, off, 64);
            }
            int m = bm + mt * 16 + lq * 4 + r;
            if (m < M && lm == 0) {
                ssi[m * NH + w].x = ps;
                s_dst[m * NH + w] = pd;
            }
        }
    // ---- h store: C/D layout col=lane&15, row=(lane>>4)*4+reg  [m89/m91]
    #pragma unroll
    for (int mt = 0; mt < 4; ++mt)
        #pragma unroll
        for (int r = 0; r < 4; ++r) {
            int m = bm + mt * 16 + lq * 4 + r;
            if (m < M) {
                #pragma unroll
                for (int nt = 0; nt < 4; ++nt)
                    h[(size_t)m * HD + wn + nt * 16 + lm] = f2bf(acc[mt][nt][r]);
            }
        }
}

// ---------------------------------------------------------------- src sums
// ONE WAVE per src node. lane = slot*4 + head: 16 slots each own a chain; the
// 4 lanes of a slot walk it in lockstep (broadcast loads), each handling one
// head. shfl_xor reduce over slots; lanes 0..3 write inv_sum. Avg chain
// length = 1. NO atomics. |e|<=~6: fp32-safe without max-subtraction.
__global__ __launch_bounds__(256) void src_sum_kernel(const int* __restrict__ head_src,
                                                      const int2* __restrict__ next_src,
                                                      float2* __restrict__ ssi,
                                                      const float* __restrict__ s_dst, int M) {
    int lane = threadIdx.x & 63;
    int n = blockIdx.x * 4 + (threadIdx.x >> 6);
    if (n >= M) return;
    int slot = lane >> 2;
    int hd = lane & 3;
    float ss = ssi[n * NH + hd].x;
    float sum = 0.f;
    int e = head_src[16 * n + slot];
    while (e != -1) {
        int2 t = next_src[e];
        float sd = s_dst[t.y * NH + hd];
        float a0 = ss + sd;
        a0 = a0 > 0.f ? a0 : 0.2f * a0;
        sum += __expf(a0);
        e = t.x;
    }
    sum += __shfl_xor(sum, 4, 64);
    sum += __shfl_xor(sum, 8, 64);
    sum += __shfl_xor(sum, 16, 64);
    sum += __shfl_xor(sum, 32, 64);
    if (lane < 4) ssi[n * NH + lane].y = 1.f / (sum + 1e-10f);
}

// ---------------------------------------------------------------- gather
// one wave per dst node; each 32-lane half walks 4 of the node's 8 chains
// (8 dependency streams/wave). Lane covers 8 channels (shortx8 = 16B h-load).
// Loads phased: {4x next} -> {4x ssi,h} -> {FMAs} so the chases overlap.
// Halves combined by cross-half shfl; single coalesced store. NO atomics.
__global__ __launch_bounds__(256) void gather_kernel(const int* __restrict__ head_dst,
                              const int2* __restrict__ next_dst,
                              const float2* __restrict__ ssi,
                              const float* __restrict__ s_dst,
                              const ushort* __restrict__ h,
                              const float* __restrict__ bias,
                              float* __restrict__ out, int M) {
    int lane = threadIdx.x & 63;
    int n = blockIdx.x * 4 + (threadIdx.x >> 6);
    if (n >= M) return;
    int half = lane >> 5;
    int l5 = lane & 31;
    int head = l5 >> 3;            // 8 lanes per head
    int c0 = l5 * 8;               // channel base 0..248
    float sdst = s_dst[n * NH + head];
    floatx4 accA = {0.f, 0.f, 0.f, 0.f}, accB = {0.f, 0.f, 0.f, 0.f};
    int e0 = head_dst[8 * n + 4 * half + 0];
    int e1 = head_dst[8 * n + 4 * half + 1];
    int e2 = head_dst[8 * n + 4 * half + 2];
    int e3 = head_dst[8 * n + 4 * half + 3];

    while (e0 != -1 || e1 != -1 || e2 != -1 || e3 != -1) {
        bool b0 = e0 != -1, b1 = e1 != -1, b2 = e2 != -1, b3 = e3 != -1;
        int2 t0, t1, t2, t3;
        // phase 1: all chain-next loads in flight
        if (b0) t0 = next_dst[e0];
        if (b1) t1 = next_dst[e1];
        if (b2) t2 = next_dst[e2];
        if (b3) t3 = next_dst[e3];
        // phase 2: all payload loads in flight
        float2 si0, si1, si2, si3;
        shortx8 h0, h1, h2, h3;
        if (b0) { si0 = ssi[(size_t)t0.y * NH + head]; h0 = *(const shortx8*)&h[(size_t)t0.y * HD + c0]; }
        if (b1) { si1 = ssi[(size_t)t1.y * NH + head]; h1 = *(const shortx8*)&h[(size_t)t1.y * HD + c0]; }
        if (b2) { si2 = ssi[(size_t)t2.y * NH + head]; h2 = *(const shortx8*)&h[(size_t)t2.y * HD + c0]; }
        if (b3) { si3 = ssi[(size_t)t3.y * NH + head]; h3 = *(const shortx8*)&h[(size_t)t3.y * HD + c0]; }
        // phase 3: compute
#define GAT_EDGE(B, SI, HU, EV, TV) do {                                       \
        if (B) {                                                               \
            float es_ = (SI).x + sdst;                                         \
            es_ = es_ > 0.f ? es_ : 0.2f * es_;                                \
            float al_ = __expf(es_) * (SI).y;                                  \
            accA.x += al_ * bf2f((ushort)(HU)[0]);                             \
            accA.y += al_ * bf2f((ushort)(HU)[1]);                             \
            accA.z += al_ * bf2f((ushort)(HU)[2]);                             \
            accA.w += al_ * bf2f((ushort)(HU)[3]);                             \
            accB.x += al_ * bf2f((ushort)(HU)[4]);                             \
            accB.y += al_ * bf2f((ushort)(HU)[5]);                             \
            accB.z += al_ * bf2f((ushort)(HU)[6]);                             \
            accB.w += al_ * bf2f((ushort)(HU)[7]);                             \
            EV = (TV).x;                                                       \
        }                                                                      \
    } while (0)
        GAT_EDGE(b0, si0, h0, e0, t0);
        GAT_EDGE(b1, si1, h1, e1, t1);
        GAT_EDGE(b2, si2, h2, e2, t2);
        GAT_EDGE(b3, si3, h3, e3, t3);
#undef GAT_EDGE
    }

    // combine the two halves (same channels, different edges)
    accA.x += __shfl_xor(accA.x, 32, 64); accA.y += __shfl_xor(accA.y, 32, 64);
    accA.z += __shfl_xor(accA.z, 32, 64); accA.w += __shfl_xor(accA.w, 32, 64);
    accB.x += __shfl_xor(accB.x, 32, 64); accB.y += __shfl_xor(accB.y, 32, 64);
    accB.z += __shfl_xor(accB.z, 32, 64); accB.w += __shfl_xor(accB.w, 32, 64);
    if (half == 0) {
        float4 b0 = *(const float4*)&bias[c0];
        float4 b1 = *(const float4*)&bias[c0 + 4];
        float4 o0 = make_float4(accA.x + b0.x, accA.y + b0.y, accA.z + b0.z, accA.w + b0.w);
        float4 o1 = make_float4(accB.x + b1.x, accB.y + b1.y, accB.z + b1.z, accB.w + b1.w);
        *(float4*)&out[(size_t)n * HD + c0] = o0;
        *(float4*)&out[(size_t)n * HD + c0 + 4] = o1;
    }
}

// ---------------------------------------------------------------- launch
extern "C" void kernel_launch(void* const* d_in, const int* in_sizes, int n_in,
                              void* d_out, int out_size, void* d_ws, size_t ws_size,
                              hipStream_t stream) {
    const float* x     = (const float*)d_in[0];
    const int2*  edges = (const int2*)d_in[1];
    const float* W     = (const float*)d_in[2];
    const float* a     = (const float*)d_in[3];
    const float* bias  = (const float*)d_in[4];
    float* out = (float*)d_out;
    const int M = in_sizes[0] / IN_DIM;   // 50000
    const int E = in_sizes[1] / 2;        // 800000

    char* p = (char*)d_ws;
    auto alloc = [&](size_t bytes) { char* q = p; p += (bytes + 255) & ~(size_t)255; return q; };
    ushort* hB       = (ushort*)alloc((size_t)M * HD * sizeof(ushort));      // 25.6 MB
    ushort* Wt       = (ushort*)alloc((size_t)HD * IN_DIM * sizeof(ushort)); // 256 KB
    float*  s_dst    = (float*)alloc((size_t)M * NH * sizeof(float));        // 800 KB
    float2* ssi      = (float2*)alloc((size_t)M * NH * sizeof(float2));      // {s_src, inv_sum}
    int*    head_src = (int*)alloc((size_t)16 * M * sizeof(int));            // 3.2 MB
    int*    head_dst = (int*)alloc((size_t)8 * M * sizeof(int));             // 1.6 MB
    int2*   next_src = (int2*)alloc((size_t)E * sizeof(int2));               // 6.4 MB
    int2*   next_dst = (int2*)alloc((size_t)E * sizeof(int2));               // 6.4 MB
    // optional bf16 copy of x (pad 64 rows so gemm's DMA tile-tail stays in-bounds)
    size_t xb_bytes = (size_t)(M + 64) * IN_DIM * sizeof(ushort);            // 51.3 MB
    ushort* xb = nullptr;
    if ((size_t)(p - (char*)d_ws) + xb_bytes <= ws_size)
        xb = (ushort*)alloc(xb_bytes);

    init_kernel<<<(16 * M + 255) / 256, 256, 0, stream>>>(head_src, head_dst, M);
    int pl_threads = xb ? (M * 64) : (E > 256 * 64 ? E : 256 * 64);
    prep_link_kernel<<<(pl_threads + 255) / 256, 256, 0, stream>>>(
        W, Wt, x, xb, edges, head_src, next_src, head_dst, next_dst, M, E);
    if (xb)
        gemm_kernel<true><<<(M + 63) / 64, 256, 0, stream>>>(x, xb, Wt, hB, a,
                                                             ssi, s_dst, M);
    else
        gemm_kernel<false><<<(M + 63) / 64, 256, 0, stream>>>(x, xb, Wt, hB, a,
                                                              ssi, s_dst, M);
    src_sum_kernel<<<(M + 3) / 4, 256, 0, stream>>>(head_src, next_src, ssi, s_dst, M);
    gather_kernel<<<(M + 3) / 4, 256, 0, stream>>>(head_dst, next_dst, ssi, s_dst,
                                                   hB, bias, out, M);
}

// Round 7
// 355.611 us; speedup vs baseline: 1.6860x; 1.0433x over previous
//
#include <hip/hip_runtime.h>
#include <math.h>

#define IN_DIM 512
#define NH 4
#define OD 64
#define HD 256   // NH*OD

typedef float  floatx4 __attribute__((ext_vector_type(4)));
typedef short  shortx8 __attribute__((ext_vector_type(8)));

__device__ __forceinline__ unsigned short f2bf(float x) {
    unsigned int u = __float_as_uint(x);
    u += 0x7fffu + ((u >> 16) & 1u);          // round-to-nearest-even
    return (unsigned short)(u >> 16);
}
__device__ __forceinline__ float bf2f(unsigned short u) {
    return __uint_as_float(((unsigned int)u) << 16);
}

// ---------------------------------------------------------------- init
// head_src (16 chains/node) / head_dst (8 chains/node) = -1 (4.8 MB);
// W fp32 [512][256] -> Wt bf16 [256][512] (gemm B operand, transposed).
__global__ void init_kernel(int* __restrict__ head_src, int* __restrict__ head_dst,
                            const float* __restrict__ W, ushort* __restrict__ Wt,
                            int M) {
    int t = blockIdx.x * blockDim.x + threadIdx.x;
    if (t < 16 * M) head_src[t] = -1;
    if (t < 8 * M) head_dst[t] = -1;
    if (t < 256 * 64) {
        int n = t >> 6;
        int k8 = (t & 63) * 8;
        shortx8 v;
        #pragma unroll
        for (int j = 0; j < 8; ++j) v[j] = (short)f2bf(W[(size_t)(k8 + j) * HD + n]);
        *(shortx8*)&Wt[(size_t)n * IN_DIM + k8] = v;
    }
}

// ---------------------------------------------------------------- GEMM + link (fused)
// Link prologue: grid-stride over edges, lock-free list push (16 chains/src,
// 8 chains/dst; payload packed into next: next_src={next,dst},
// next_dst={next,src}; payload writes coalesced by edge id). The atomic
// drain is fabric-RMW-bound with ~0 VALU/BW use (r4: VALUBusy 2.5%), so it
// overlaps with other waves' MFMA phase on the same CUs.
// GEMM: h_bf16 = bf16(x) @ W, tile 64(M) x 256(N), BK=64, 4 waves (64m x 64n
// each). Wave w's columns == head w, so s_src/s_dst come from the fp32
// accumulators in-epilogue via a 16-lane shfl reduction.
__global__ __launch_bounds__(256) void gemm_link_kernel(
        const float* __restrict__ x, const ushort* __restrict__ Wt,
        ushort* __restrict__ h, const float* __restrict__ a,
        float2* __restrict__ ssi, float* __restrict__ s_dst,
        const int2* __restrict__ edges,
        int* __restrict__ head_src, int2* __restrict__ next_src,
        int* __restrict__ head_dst, int2* __restrict__ next_dst,
        int M, int E) {
    __shared__ ushort As[64 * 64];     // [row m][64 k]  8 KB
    __shared__ ushort Bs[256 * 64];    // [row n][64 k] 32 KB
    const int tid = threadIdx.x;

    // ---- link prologue (independent of GEMM; hidden by wave interleaving)
    {
        const int T = gridDim.x * 256;
        for (int i = blockIdx.x * 256 + tid; i < E; i += T) {
            int2 e = edges[i];
            int ps = atomicExch(&head_src[16 * e.x + (i & 15)], i);
            next_src[i] = make_int2(ps, e.y);
            int pd = atomicExch(&head_dst[8 * e.y + (i & 7)], i);
            next_dst[i] = make_int2(pd, e.x);
        }
    }

    const int lane = tid & 63;
    const int w = tid >> 6;
    const int bm = blockIdx.x * 64;
    const int wn = w * 64;
    const int lm = lane & 15;          // fragment row
    const int lq = lane >> 4;          // quad
    floatx4 acc[4][4];
    #pragma unroll
    for (int i = 0; i < 4; ++i)
        #pragma unroll
        for (int j = 0; j < 4; ++j) acc[i][j] = (floatx4){0.f, 0.f, 0.f, 0.f};

    for (int k0 = 0; k0 < IN_DIM; k0 += 64) {
        #pragma unroll
        for (int j = 0; j < 2; ++j) {
            int ch = tid * 2 + j;
            int row = ch >> 3;
            int c = (ch & 7) ^ (row & 7);        // XOR swizzle (2-way b128: free, m136)
            int gr = bm + row;
            shortx8 v = (shortx8){0, 0, 0, 0, 0, 0, 0, 0};
            if (gr < M) {
                const float* gp = &x[(size_t)gr * IN_DIM + k0 + c * 8];
                float4 v0 = *(const float4*)gp;
                float4 v1 = *(const float4*)(gp + 4);
                v[0] = (short)f2bf(v0.x); v[1] = (short)f2bf(v0.y);
                v[2] = (short)f2bf(v0.z); v[3] = (short)f2bf(v0.w);
                v[4] = (short)f2bf(v1.x); v[5] = (short)f2bf(v1.y);
                v[6] = (short)f2bf(v1.z); v[7] = (short)f2bf(v1.w);
            }
            *(shortx8*)&As[ch * 8] = v;
        }
        #pragma unroll
        for (int j = 0; j < 8; ++j) {
            int ch = j * 256 + tid;
            int row = ch >> 3;
            int c = (ch & 7) ^ (row & 7);
            const ushort* gp = &Wt[(size_t)row * IN_DIM + k0 + c * 8];
            __builtin_amdgcn_global_load_lds(
                (const __attribute__((address_space(1))) void*)gp,
                (__attribute__((address_space(3))) void*)&Bs[(size_t)(j * 256 + wn) * 8],
                16, 0, 0);
        }
        __syncthreads();
        #pragma unroll
        for (int kk = 0; kk < 2; ++kk) {
            shortx8 af[4], bfr[4];
            #pragma unroll
            for (int mt = 0; mt < 4; ++mt) {
                int row = mt * 16 + lm;
                int c = (kk * 4 + lq) ^ (row & 7);
                af[mt] = *(const shortx8*)&As[row * 64 + c * 8];
            }
            #pragma unroll
            for (int nt = 0; nt < 4; ++nt) {
                int row = wn + nt * 16 + lm;
                int c = (kk * 4 + lq) ^ (row & 7);
                bfr[nt] = *(const shortx8*)&Bs[row * 64 + c * 8];
            }
            #pragma unroll
            for (int mt = 0; mt < 4; ++mt)
                #pragma unroll
                for (int nt = 0; nt < 4; ++nt)
                    acc[mt][nt] = __builtin_amdgcn_mfma_f32_16x16x32_bf16(
                        af[mt], bfr[nt], acc[mt][nt], 0, 0, 0);
        }
        __syncthreads();
    }
    // ---- fused scores: s_src[m,w], s_dst[m,w] from fp32 acc
    float as_l[4], ad_l[4];
    #pragma unroll
    for (int nt = 0; nt < 4; ++nt) {
        as_l[nt] = a[w * 2 * OD + nt * 16 + lm];
        ad_l[nt] = a[w * 2 * OD + OD + nt * 16 + lm];
    }
    #pragma unroll
    for (int mt = 0; mt < 4; ++mt)
        #pragma unroll
        for (int r = 0; r < 4; ++r) {
            float ps = 0.f, pd = 0.f;
            #pragma unroll
            for (int nt = 0; nt < 4; ++nt) {
                float v = acc[mt][nt][r];
                ps += v * as_l[nt];
                pd += v * ad_l[nt];
            }
            #pragma unroll
            for (int off = 1; off < 16; off <<= 1) {
                ps += __shfl_xor(ps, off, 64);
                pd += __shfl_xor(pd, off, 64);
            }
            int m = bm + mt * 16 + lq * 4 + r;
            if (m < M && lm == 0) {
                ssi[m * NH + w].x = ps;
                s_dst[m * NH + w] = pd;
            }
        }
    // ---- h store: C/D layout col=lane&15, row=(lane>>4)*4+reg  [m89/m91]
    #pragma unroll
    for (int mt = 0; mt < 4; ++mt)
        #pragma unroll
        for (int r = 0; r < 4; ++r) {
            int m = bm + mt * 16 + lq * 4 + r;
            if (m < M) {
                #pragma unroll
                for (int nt = 0; nt < 4; ++nt)
                    h[(size_t)m * HD + wn + nt * 16 + lm] = f2bf(acc[mt][nt][r]);
            }
        }
}

// ---------------------------------------------------------------- src sums
// ONE WAVE per src node. lane = slot*4 + head: 16 slots each own a chain; the
// 4 lanes of a slot walk it in lockstep (broadcast loads), each handling one
// head. shfl_xor reduce over slots; lanes 0..3 write inv_sum. Avg chain
// length = 1. NO atomics. |e|<=~6: fp32-safe without max-subtraction.
__global__ __launch_bounds__(256) void src_sum_kernel(const int* __restrict__ head_src,
                                                      const int2* __restrict__ next_src,
                                                      float2* __restrict__ ssi,
                                                      const float* __restrict__ s_dst, int M) {
    int lane = threadIdx.x & 63;
    int n = blockIdx.x * 4 + (threadIdx.x >> 6);
    if (n >= M) return;
    int slot = lane >> 2;
    int hd = lane & 3;
    float ss = ssi[n * NH + hd].x;
    float sum = 0.f;
    int e = head_src[16 * n + slot];
    while (e != -1) {
        int2 t = next_src[e];
        float sd = s_dst[t.y * NH + hd];
        float a0 = ss + sd;
        a0 = a0 > 0.f ? a0 : 0.2f * a0;
        sum += __expf(a0);
        e = t.x;
    }
    sum += __shfl_xor(sum, 4, 64);
    sum += __shfl_xor(sum, 8, 64);
    sum += __shfl_xor(sum, 16, 64);
    sum += __shfl_xor(sum, 32, 64);
    if (lane < 4) ssi[n * NH + lane].y = 1.f / (sum + 1e-10f);
}

// ---------------------------------------------------------------- gather
// one wave per dst node; each 32-lane half walks 4 of the node's 8 chains
// (8 dependency streams/wave). Lane covers 8 channels (shortx8 = 16B h-load).
// Loads phased: {4x next} -> {4x ssi,h} -> {FMAs} so the chases overlap.
// Halves combined by cross-half shfl; single coalesced store. NO atomics.
__global__ __launch_bounds__(256) void gather_kernel(const int* __restrict__ head_dst,
                              const int2* __restrict__ next_dst,
                              const float2* __restrict__ ssi,
                              const float* __restrict__ s_dst,
                              const ushort* __restrict__ h,
                              const float* __restrict__ bias,
                              float* __restrict__ out, int M) {
    int lane = threadIdx.x & 63;
    int n = blockIdx.x * 4 + (threadIdx.x >> 6);
    if (n >= M) return;
    int half = lane >> 5;
    int l5 = lane & 31;
    int head = l5 >> 3;            // 8 lanes per head
    int c0 = l5 * 8;               // channel base 0..248
    float sdst = s_dst[n * NH + head];
    floatx4 accA = {0.f, 0.f, 0.f, 0.f}, accB = {0.f, 0.f, 0.f, 0.f};
    int e0 = head_dst[8 * n + 4 * half + 0];
    int e1 = head_dst[8 * n + 4 * half + 1];
    int e2 = head_dst[8 * n + 4 * half + 2];
    int e3 = head_dst[8 * n + 4 * half + 3];

    while (e0 != -1 || e1 != -1 || e2 != -1 || e3 != -1) {
        bool b0 = e0 != -1, b1 = e1 != -1, b2 = e2 != -1, b3 = e3 != -1;
        int2 t0, t1, t2, t3;
        // phase 1: all chain-next loads in flight
        if (b0) t0 = next_dst[e0];
        if (b1) t1 = next_dst[e1];
        if (b2) t2 = next_dst[e2];
        if (b3) t3 = next_dst[e3];
        // phase 2: all payload loads in flight
        float2 si0, si1, si2, si3;
        shortx8 h0, h1, h2, h3;
        if (b0) { si0 = ssi[(size_t)t0.y * NH + head]; h0 = *(const shortx8*)&h[(size_t)t0.y * HD + c0]; }
        if (b1) { si1 = ssi[(size_t)t1.y * NH + head]; h1 = *(const shortx8*)&h[(size_t)t1.y * HD + c0]; }
        if (b2) { si2 = ssi[(size_t)t2.y * NH + head]; h2 = *(const shortx8*)&h[(size_t)t2.y * HD + c0]; }
        if (b3) { si3 = ssi[(size_t)t3.y * NH + head]; h3 = *(const shortx8*)&h[(size_t)t3.y * HD + c0]; }
        // phase 3: compute
#define GAT_EDGE(B, SI, HU, EV, TV) do {                                       \
        if (B) {                                                               \
            float es_ = (SI).x + sdst;                                         \
            es_ = es_ > 0.f ? es_ : 0.2f * es_;                                \
            float al_ = __expf(es_) * (SI).y;                                  \
            accA.x += al_ * bf2f((ushort)(HU)[0]);                             \
            accA.y += al_ * bf2f((ushort)(HU)[1]);                             \
            accA.z += al_ * bf2f((ushort)(HU)[2]);                             \
            accA.w += al_ * bf2f((ushort)(HU)[3]);                             \
            accB.x += al_ * bf2f((ushort)(HU)[4]);                             \
            accB.y += al_ * bf2f((ushort)(HU)[5]);                             \
            accB.z += al_ * bf2f((ushort)(HU)[6]);                             \
            accB.w += al_ * bf2f((ushort)(HU)[7]);                             \
            EV = (TV).x;                                                       \
        }                                                                      \
    } while (0)
        GAT_EDGE(b0, si0, h0, e0, t0);
        GAT_EDGE(b1, si1, h1, e1, t1);
        GAT_EDGE(b2, si2, h2, e2, t2);
        GAT_EDGE(b3, si3, h3, e3, t3);
#undef GAT_EDGE
    }

    // combine the two halves (same channels, different edges)
    accA.x += __shfl_xor(accA.x, 32, 64); accA.y += __shfl_xor(accA.y, 32, 64);
    accA.z += __shfl_xor(accA.z, 32, 64); accA.w += __shfl_xor(accA.w, 32, 64);
    accB.x += __shfl_xor(accB.x, 32, 64); accB.y += __shfl_xor(accB.y, 32, 64);
    accB.z += __shfl_xor(accB.z, 32, 64); accB.w += __shfl_xor(accB.w, 32, 64);
    if (half == 0) {
        float4 b0 = *(const float4*)&bias[c0];
        float4 b1 = *(const float4*)&bias[c0 + 4];
        float4 o0 = make_float4(accA.x + b0.x, accA.y + b0.y, accA.z + b0.z, accA.w + b0.w);
        float4 o1 = make_float4(accB.x + b1.x, accB.y + b1.y, accB.z + b1.z, accB.w + b1.w);
        *(float4*)&out[(size_t)n * HD + c0] = o0;
        *(float4*)&out[(size_t)n * HD + c0 + 4] = o1;
    }
}

// ---------------------------------------------------------------- launch
extern "C" void kernel_launch(void* const* d_in, const int* in_sizes, int n_in,
                              void* d_out, int out_size, void* d_ws, size_t ws_size,
                              hipStream_t stream) {
    const float* x     = (const float*)d_in[0];
    const int2*  edges = (const int2*)d_in[1];
    const float* W     = (const float*)d_in[2];
    const float* a     = (const float*)d_in[3];
    const float* bias  = (const float*)d_in[4];
    float* out = (float*)d_out;
    const int M = in_sizes[0] / IN_DIM;   // 50000
    const int E = in_sizes[1] / 2;        // 800000

    char* p = (char*)d_ws;
    auto alloc = [&](size_t bytes) { char* q = p; p += (bytes + 255) & ~(size_t)255; return q; };
    ushort* hB       = (ushort*)alloc((size_t)M * HD * sizeof(ushort));      // 25.6 MB
    ushort* Wt       = (ushort*)alloc((size_t)HD * IN_DIM * sizeof(ushort)); // 256 KB
    float*  s_dst    = (float*)alloc((size_t)M * NH * sizeof(float));        // 800 KB
    float2* ssi      = (float2*)alloc((size_t)M * NH * sizeof(float2));      // {s_src, inv_sum}
    int*    head_src = (int*)alloc((size_t)16 * M * sizeof(int));            // 3.2 MB
    int*    head_dst = (int*)alloc((size_t)8 * M * sizeof(int));             // 1.6 MB
    int2*   next_src = (int2*)alloc((size_t)E * sizeof(int2));               // 6.4 MB
    int2*   next_dst = (int2*)alloc((size_t)E * sizeof(int2));               // 6.4 MB

    init_kernel<<<(16 * M + 255) / 256, 256, 0, stream>>>(head_src, head_dst, W, Wt, M);
    gemm_link_kernel<<<(M + 63) / 64, 256, 0, stream>>>(
        x, Wt, hB, a, ssi, s_dst, edges,
        head_src, next_src, head_dst, next_dst, M, E);
    src_sum_kernel<<<(M + 3) / 4, 256, 0, stream>>>(head_src, next_src, ssi, s_dst, M);
    gather_kernel<<<(M + 3) / 4, 256, 0, stream>>>(head_dst, next_dst, ssi, s_dst,
                                                   hB, bias, out, M);
}